// Round 18
// baseline (209.163 us; speedup 1.0000x reference)
//
#include <hip/hip_runtime.h>

typedef unsigned short u16;
typedef unsigned int   u32;
typedef unsigned long long u64;

typedef __bf16 bf16x8 __attribute__((ext_vector_type(8)));
typedef float  f32x4  __attribute__((ext_vector_type(4)));

#define B_ROWS   16384
#define D_DIM    256
#define H_DIM    8192
#define THR_C    2.35f
#define QCAP     48          // per-(row, quarter-col-segment) candidate cap

// workspace byte offsets (~29.7 MiB)
#define SAE_OFF    0u          // u16 [16384*256]      sae_in bf16
#define WENCB_OFF  8388608u    // u16 [8192*256]       W_enc bf16
#define WDECB_OFF  12582912u   // u16 [8192*256]       W_dec bf16
#define TROW_OFF   16777216u   // f32 [16384]          per-row threshold
#define CAND_OFF   16842752u   // u32 [16384*4*QCAP]   candidates (bf16val<<16|col)
#define CGQ_OFF    29425664u   // u32 [16384*4]        per-(row,q) counts
#define COLSUM_OFF 29687808u   // f32 [256]
#define SUMSQ_OFF  29688832u   // f32 [1]
#define SSE_OFF    29688836u   // f32 [1]

__device__ __forceinline__ u16 f2bf(float f) {
  u32 u = __float_as_uint(f);
  u32 r = (u + 0x7fffu + ((u >> 16) & 1u)) >> 16;   // RNE
  return (u16)r;
}
__device__ __forceinline__ float bf2f(u16 h) {
  return __uint_as_float(((u32)h) << 16);
}

__device__ __forceinline__ void async_copy16(const void* g, void* l) {
  __builtin_amdgcn_global_load_lds((const __attribute__((address_space(1))) u32*)g,
                                   (__attribute__((address_space(3))) u32*)l,
                                   16, 0, 0);
}

// ---------------- zero counts + accumulators ----------------
__global__ void k_zero(float* counts_out, float* accums) {
  int i = blockIdx.x * 256 + threadIdx.x;
  if (i < H_DIM + 1) counts_out[i] = 0.f;
  if (i < 258) accums[i] = 0.f;
}

// ---------------- merged prep: blocks [0,4096) convert W_enc/W_dec -> bf16;
// ---------------- blocks [4096,4608) do x -> sae bf16 + trow + colsum + sumsq ----------------
__global__ __launch_bounds__(256) void k_prep(const float* __restrict__ x,
                                              const float* __restrict__ bdec,
                                              const float4* __restrict__ wenc,
                                              const float4* __restrict__ wdec,
                                              u16* __restrict__ sae,
                                              float* __restrict__ trow,
                                              float* __restrict__ colsum,
                                              float* __restrict__ sumsq,
                                              ushort4* __restrict__ wencb,
                                              ushort4* __restrict__ wdecb) {
  __shared__ float cssh[256];
  __shared__ float sqsh[4];
  const int bx = blockIdx.x;
  if (bx < 4096) {                       // W conversion branch (no barriers)
    const int i = bx * 256 + threadIdx.x;
    const int half = H_DIM * D_DIM / 4;
    float4 v;
    if (i < half) v = wenc[i]; else v = wdec[i - half];
    ushort4 o;
    o.x = f2bf(v.x); o.y = f2bf(v.y); o.z = f2bf(v.z); o.w = f2bf(v.w);
    if (i < half) wencb[i] = o; else wdecb[i - half] = o;
    return;
  }
  const int blk = bx - 4096;             // x-prep branch
  const int tid = threadIdx.x;
  const int l = tid & 63, w = tid >> 6;
  const float4 bd4 = *(const float4*)(bdec + l * 4);
  float4 cs4 = {0.f, 0.f, 0.f, 0.f};
  float sq = 0.f;
  for (int i = 0; i < 8; ++i) {
    const int row = blk * 32 + w * 8 + i;
    const float4 x4 = *(const float4*)(x + (size_t)row * D_DIM + l * 4);
    float4 s4 = {x4.x - bd4.x, x4.y - bd4.y, x4.z - bd4.z, x4.w - bd4.w};
    ushort4 o;
    o.x = f2bf(s4.x); o.y = f2bf(s4.y); o.z = f2bf(s4.z); o.w = f2bf(s4.w);
    *(ushort4*)(sae + (size_t)row * D_DIM + l * 4) = o;
    cs4.x += x4.x; cs4.y += x4.y; cs4.z += x4.z; cs4.w += x4.w;
    sq += x4.x * x4.x + x4.y * x4.y + x4.z * x4.z + x4.w * x4.w;
    float ss = s4.x * s4.x + s4.y * s4.y + s4.z * s4.z + s4.w * s4.w;
#pragma unroll
    for (int off = 32; off > 0; off >>= 1) ss += __shfl_xor(ss, off);
    if (l == 0) trow[row] = THR_C * sqrtf(ss * (1.0f / 256.0f));
  }
  if (w == 0) { cssh[l * 4 + 0] = cs4.x; cssh[l * 4 + 1] = cs4.y; cssh[l * 4 + 2] = cs4.z; cssh[l * 4 + 3] = cs4.w; }
  __syncthreads();
#pragma unroll
  for (int ww = 1; ww < 4; ++ww) {
    if (w == ww) { cssh[l * 4 + 0] += cs4.x; cssh[l * 4 + 1] += cs4.y; cssh[l * 4 + 2] += cs4.z; cssh[l * 4 + 3] += cs4.w; }
    __syncthreads();
  }
#pragma unroll
  for (int off = 32; off > 0; off >>= 1) sq += __shfl_xor(sq, off);
  if (l == 0) sqsh[w] = sq;
  __syncthreads();
  atomicAdd(&colsum[tid], cssh[tid]);
  if (tid == 0) atomicAdd(sumsq, sqsh[0] + sqsh[1] + sqsh[2] + sqsh[3]);
}

// ---------------- encoder GEMM + threshold filter ----------------
// r17 counted-vmcnt 3-ring + two refinements:
//  (a) stage(ci+2) issued right after the barrier (full compute-phase of
//      extra flight time). Per-wave VMEM issue order per iter becomes
//      [stage(ci+2) x2, benc(ci)], so top-of-iter wait is vmcnt(3):
//      retires stage(ci) + benc(ci-2), leaves {stage(ci+1), benc(ci-1)}.
//      Safety: barrier at top of iter ci proves all waves finished
//      compute(ci-1) before buf[(ci-1)%3] is overwritten (stage is
//      post-barrier). Tail: ci=63 -> vmcnt(0).
//  (b) s_setprio(1) around the MFMA cluster (T5; counted-vmcnt schedule
//      gives cross-block wave role diversity for the arbiter to exploit).
__global__ __launch_bounds__(512, 4) void k_gemm(const u16* __restrict__ sae,
                                                 const u16* __restrict__ wenc,
                                                 const float* __restrict__ benc,
                                                 const float* __restrict__ trow,
                                                 u32* __restrict__ cand,
                                                 u32* __restrict__ cgq) {
  __shared__ __align__(16) u16 ldsw[3][8192];   // 3 x 16 KiB ring (32 cols x 256 k)
  __shared__ u32 lcand[128 * QCAP];             // 24 KiB candidate buffer
  __shared__ u32 lcnt[128];
  const int tid = threadIdx.x;
  const int l   = tid & 63;
  const int w   = tid >> 6;
  const int bid = blockIdx.x;
  const int q   = bid & 3;
  const int m   = bid >> 2;
  const int wr  = w & 3;
  const int wc  = w >> 2;
  const int rbase = m * 128 + wr * 32;
  const int kc  = l >> 4;    // 0..3
  const int r16 = l & 15;

  if (tid < 128) lcnt[tid] = 0u;

  // A fragments: rows rbase + fr*16 + r16, k = ks*32 + kc*8 + j
  bf16x8 a[2][8];
#pragma unroll
  for (int fr = 0; fr < 2; ++fr) {
    const u16* ap = sae + (size_t)(rbase + fr * 16 + r16) * 256 + kc * 8;
#pragma unroll
    for (int ks = 0; ks < 8; ++ks)
      a[fr][ks] = *(const bf16x8*)(ap + ks * 32);
  }
  float trw[2][4];
#pragma unroll
  for (int fr = 0; fr < 2; ++fr)
#pragma unroll
    for (int rr = 0; rr < 4; ++rr)
      trw[fr][rr] = trow[rbase + fr * 16 + kc * 4 + rr];

  const char* wbytes = (const char*)wenc;
  auto stage = [&](int ci, int buf) {
    const int gcol0 = q * 2048 + ci * 32;
#pragma unroll
    for (int i = 0; i < 2; ++i) {
      int L    = i * 8192 + tid * 16;          // linear LDS byte (0..16383)
      int col  = L >> 9;                       // 0..31
      int pblk = (L >> 4) & 31;                // physical 16B chunk in col
      int cblk = pblk ^ (col & 15);            // inverse swizzle on source
      const void* src = wbytes + (size_t)(gcol0 + col) * 512 + (size_t)cblk * 16;
      void* dst = (char*)(&ldsw[buf][0]) + i * 8192 + w * 1024;   // wave-uniform base
      async_copy16(src, dst);
    }
  };

  stage(0, 0);
  stage(1, 1);
  __syncthreads();     // one-time full drain: lcnt init visible + tiles 0,1 ready

  const f32x4 fzero = {0.f, 0.f, 0.f, 0.f};
  int cur = 0;
  for (int ci = 0; ci < 64; ++ci) {
    if (ci < 63) {
      asm volatile("s_waitcnt vmcnt(3)" ::: "memory");
    } else {
      asm volatile("s_waitcnt vmcnt(0)" ::: "memory");
    }
    __builtin_amdgcn_sched_barrier(0);
    __builtin_amdgcn_s_barrier();              // all waves' tile-ci loads landed

    // stage tile ci+2 into buf[(ci+2)%3] = buf[(ci-1)%3]: all waves passed this
    // iter's barrier => all finished compute(ci-1) reads of that buffer.
    if (ci + 2 < 64) {
      const int sb = cur == 0 ? 2 : cur - 1;   // (ci+2)%3
      stage(ci + 2, sb);
    }

    const int gcol0 = q * 2048 + ci * 32;
    const char* bufc = (const char*)(&ldsw[cur][0]);

    const float be = benc[gcol0 + wc * 16 + r16];

    f32x4 acc[2];
    acc[0] = fzero; acc[1] = fzero;

    __builtin_amdgcn_s_setprio(1);
#pragma unroll
    for (int ks = 0; ks < 8; ++ks) {
      const int colL = wc * 16 + r16;          // 0..31
      const int pb = (ks * 4 + kc) ^ r16;      // swizzled 16B chunk
      const bf16x8 bfrag = *(const bf16x8*)(bufc + (size_t)colL * 512 + (size_t)pb * 16);
#pragma unroll
      for (int fr = 0; fr < 2; ++fr)
        acc[fr] = __builtin_amdgcn_mfma_f32_16x16x32_bf16(a[fr][ks], bfrag, acc[fr], 0, 0, 0);
    }
    __builtin_amdgcn_s_setprio(0);

    // epilogue: relu(score+b_enc) > t_row -> append packed candidate to LDS
#pragma unroll
    for (int fr = 0; fr < 2; ++fr) {
#pragma unroll
      for (int rr = 0; rr < 4; ++rr) {
        float v = acc[fr][rr] + be;
        if (v > trw[fr][rr]) {
          const int rowl = wr * 32 + fr * 16 + kc * 4 + rr;
          const int colg = gcol0 + wc * 16 + r16;
          u32 pos = atomicAdd(&lcnt[rowl], 1u);
          if (pos < (u32)QCAP)
            lcand[rowl * QCAP + pos] = ((u32)f2bf(v) << 16) | (u32)colg;
        }
      }
    }
    cur = (cur == 2) ? 0 : cur + 1;
  }

  __syncthreads();     // all epilogue LDS atomics visible before flush

  // coalesced flush: counts + valid candidates
  if (tid < 128) cgq[(size_t)(m * 128 + tid) * 4 + q] = lcnt[tid];
  const int rowl = tid >> 2;                   // 4 threads per row
  const u32 cnt = lcnt[rowl];
  const u32 lim = cnt < (u32)QCAP ? cnt : (u32)QCAP;
  u32* dst = cand + ((size_t)(m * 128 + rowl) * 4 + q) * QCAP;
#pragma unroll
  for (int j = 0; j < QCAP / 4; ++j) {
    const u32 s = (u32)(tid & 3) + 4u * j;
    if (s < lim) dst[s] = lcand[rowl * QCAP + s];
  }
}

// ---------------- wave-wide bitonic sorts (ascending across 64 lanes) ----------------
__device__ __forceinline__ u64 sort64(u64 v, int l) {
#pragma unroll
  for (int k = 2; k <= 64; k <<= 1) {
#pragma unroll
    for (int j = k >> 1; j > 0; j >>= 1) {
      u64 o = __shfl_xor(v, j);
      const bool up    = ((l & k) == 0);
      const bool lower = ((l & j) == 0);
      u64 mn = v < o ? v : o;
      u64 mx = v < o ? o : v;
      v = (up == lower) ? mn : mx;
    }
  }
  return v;
}
__device__ __forceinline__ u32 sort64u(u32 v, int l) {
#pragma unroll
  for (int k = 2; k <= 64; k <<= 1) {
#pragma unroll
    for (int j = k >> 1; j > 0; j >>= 1) {
      u32 o = __shfl_xor(v, j);
      const bool up    = ((l & k) == 0);
      const bool lower = ((l & j) == 0);
      u32 mn = v < o ? v : o;
      u32 mx = v < o ? o : v;
      v = (up == lower) ? mn : mx;
    }
  }
  return v;
}

// ---------------- fused: exact top-32 (wave-cooperative f32 rescore of ranks 25..40)
// ---------------- + counts + decode + sse (r11 champion, byte-identical) ----------------
__global__ __launch_bounds__(256) void k_seldec(const u32* __restrict__ cand,
                                                const u32* __restrict__ cgq,
                                                const u16* __restrict__ sae,
                                                const u16* __restrict__ wenc,
                                                const float* __restrict__ benc,
                                                const float* __restrict__ wencf,
                                                const u16* __restrict__ wdecb,
                                                const float* __restrict__ bdec,
                                                const float* __restrict__ x,
                                                float* __restrict__ out,
                                                float* __restrict__ counts,
                                                float* __restrict__ sse) {
  __shared__ float sh_s[4][256];
  __shared__ float essh[4];
  const int l = threadIdx.x & 63;
  const int w = threadIdx.x >> 6;
  const int row = blockIdx.x * 4 + w;
  // stage s = x - b_dec (f32) for this row into LDS (wave-private region)
  const float4 x4  = *(const float4*)(x + (size_t)row * D_DIM + l * 4);
  const float4 bd4 = *(const float4*)(bdec + l * 4);
  {
    float4 s4 = {x4.x - bd4.x, x4.y - bd4.y, x4.z - bd4.z, x4.w - bd4.w};
    *(float4*)(&sh_s[w][l * 4]) = s4;
  }

  const uint4 c4 = *(const uint4*)(cgq + (size_t)row * 4);
  const bool ovf = (c4.x > (u32)QCAP) | (c4.y > (u32)QCAP) | (c4.z > (u32)QCAP) | (c4.w > (u32)QCAP);
  const u32 cum0 = c4.x, cum1 = cum0 + c4.y, cum2 = cum1 + c4.z;
  const u32 T = cum2 + c4.w;
  u64 v;
  if (!ovf && T >= 32u) {          // wave-uniform branch (row is per-wave)
    const u32* cb = cand + (size_t)row * 4 * QCAP;
    auto fetch = [&](u32 p) -> u32 {
      u32 qi, off;
      if (p < cum0)      { qi = 0; off = p; }
      else if (p < cum1) { qi = 1; off = p - cum0; }
      else if (p < cum2) { qi = 2; off = p - cum1; }
      else               { qi = 3; off = p - cum2; }
      return cb[qi * QCAP + off];
    };
    u32 key = ((u32)l < T) ? fetch((u32)l) : 0u;
    key = sort64u(key, l);
    for (u32 p = 64; p < T; p += 64) {
      const u32 pp = p + (u32)l;
      u32 u = (pp < T) ? fetch(pp) : 0u;
      u = sort64u(u, l);
      u32 ur = __shfl(u, 63 - l);
      key = key > ur ? key : ur;      // top-64 of union (bitonic)
      key = sort64u(key, l);
    }
    // keys ascending: lane 63 = bf16-rank 1. Expand to u64: f32 bit pattern
    // (bf16 bits, already <<16 inside key) goes in the HIGH 32 bits (<<32).
    v = key ? ((((u64)(key & 0xffff0000u)) << 32) | (u64)(key & 0x1fffu)) : 0ull;
    // Wave-cooperative f32 rescore of the 16 boundary candidates (bf16 ranks
    // 25..40, held by lanes 24..39). 4 groups x 16 lanes; each group computes
    // 4 candidates; coalesced 16-float reads + 4-step shfl_xor group reduce.
    // Ranks 1..24 / 41+ keep bf16 values (in/out-of-set by ~30-sigma margins).
    const int g  = l >> 4;
    const int gl = l & 15;
    const float* srow = &sh_s[w][gl * 16];
    const float4 sv0 = *(const float4*)(srow + 0);
    const float4 sv1 = *(const float4*)(srow + 4);
    const float4 sv2 = *(const float4*)(srow + 8);
    const float4 sv3 = *(const float4*)(srow + 12);
    auto cscore = [&](int j) -> float {
      const u32 kj = (u32)__shfl((int)key, 24 + g * 4 + j);   // candidate key
      const u32 ti = kj & 0x1fffu;
      const float* wrow = wencf + (size_t)ti * D_DIM + gl * 16;
      const float4 w0 = *(const float4*)(wrow + 0);
      const float4 w1 = *(const float4*)(wrow + 4);
      const float4 w2 = *(const float4*)(wrow + 8);
      const float4 w3 = *(const float4*)(wrow + 12);
      float p = sv0.x * w0.x + sv0.y * w0.y + sv0.z * w0.z + sv0.w * w0.w
              + sv1.x * w1.x + sv1.y * w1.y + sv1.z * w1.z + sv1.w * w1.w
              + sv2.x * w2.x + sv2.y * w2.y + sv2.z * w2.z + sv2.w * w2.w
              + sv3.x * w3.x + sv3.y * w3.y + sv3.z * w3.z + sv3.w * w3.w;
      p += __shfl_xor(p, 1);
      p += __shfl_xor(p, 2);
      p += __shfl_xor(p, 4);
      p += __shfl_xor(p, 8);
      return p;                     // all 16 lanes of the group hold the dot
    };
    const float r0 = cscore(0);
    const float r1 = cscore(1);
    const float r2 = cscore(2);
    const float r3 = cscore(3);
    {
      // deliver candidate c's score to owner lane 24+c (c = g*4+j computed in
      // group c>>2): 4 shfl broadcasts + select. All lanes execute the shfls.
      const int c  = (l - 24) & 63;
      const int sg = ((c >> 2) & 3) * 16;
      const float t0 = __shfl(r0, sg);
      const float t1 = __shfl(r1, sg);
      const float t2 = __shfl(r2, sg);
      const float t3 = __shfl(r3, sg);
      const int cm = c & 3;
      const float ps = cm == 0 ? t0 : (cm == 1 ? t1 : (cm == 2 ? t2 : t3));
      if (l >= 24 && l < 40 && key != 0u) {
        const u32 ti = key & 0x1fffu;
        const float ns = fmaxf(ps + benc[ti], 0.f);   // relu; keys stay non-negative
        v = ((u64)__float_as_uint(ns) << 32) | ti;
      }
    }
    v = sort64(v, l);
  } else {
    // statistically unreachable fallback: exact full-row recompute (bf16)
    v = 0ull;
    const u16* ap = sae + (size_t)row * 256;
    for (int c0 = 0; c0 < H_DIM; c0 += 64) {
      const int col = c0 + l;
      const u16* wp = wenc + (size_t)col * 256;
      float s = benc[col];
      for (int kk = 0; kk < 256; ++kk) s += bf2f(ap[kk]) * bf2f(wp[kk]);
      s = fmaxf(s, 0.f);
      u64 u = ((u64)__float_as_uint(s) << 32) | (u32)col;
      u = sort64(u, l);
      if (c0 == 0) {
        v = u;
      } else {
        u64 ur = __shfl(u, 63 - l);
        v = v > ur ? v : ur;
        v = sort64(v, l);
      }
    }
  }
  // lanes 32..63 hold the top-32 (ascending): per-latent counts
  if (l >= 32) {
    const u32 idx = (u32)(v & 0xffffffffu);
    atomicAdd(&counts[idx], 1.0f);
  }
  // decode from bf16 W_dec (r4-validated shfl-broadcast pattern)
  float ax = 0.f, ay = 0.f, az = 0.f, aw2 = 0.f;
#pragma unroll 8
  for (int j = 0; j < 32; ++j) {
    const u64 t = __shfl(v, 32 + j);
    const float tv = __uint_as_float((u32)(t >> 32));
    const u32 ti = (u32)(t & 0x1fffu);
    const ushort4 wv = *(const ushort4*)(wdecb + (size_t)ti * 256 + l * 4);
    ax += tv * bf2f(wv.x); ay += tv * bf2f(wv.y);
    az += tv * bf2f(wv.z); aw2 += tv * bf2f(wv.w);
  }
  float4 xr;
  xr.x = ax + bd4.x; xr.y = ay + bd4.y; xr.z = az + bd4.z; xr.w = aw2 + bd4.w;
  *(float4*)(out + (size_t)row * 256 + l * 4) = xr;
  const float e0 = xr.x - x4.x, e1 = xr.y - x4.y, e2 = xr.z - x4.z, e3 = xr.w - x4.w;
  float es = e0 * e0 + e1 * e1 + e2 * e2 + e3 * e3;
#pragma unroll
  for (int off = 32; off > 0; off >>= 1) es += __shfl_xor(es, off);
  if (l == 0) essh[w] = es;
  __syncthreads();
  if (threadIdx.x == 0) atomicAdd(sse, essh[0] + essh[1] + essh[2] + essh[3]);
}

// ---------------- fvu ----------------
__global__ __launch_bounds__(256) void k_fvu(const float* __restrict__ colsum,
                                             const float* __restrict__ sumsq,
                                             const float* __restrict__ sse,
                                             float* __restrict__ out) {
  __shared__ float red[4];
  const int tid = threadIdx.x;
  const int l = tid & 63;
  const int w = tid >> 6;
  const float c = colsum[tid];
  float p = c * c;
#pragma unroll
  for (int off = 32; off > 0; off >>= 1) p += __shfl_xor(p, off);
  if (l == 0) red[w] = p;
  __syncthreads();
  if (tid == 0) {
    const float tv = sumsq[0] - (red[0] + red[1] + red[2] + red[3]) * (1.0f / 16384.0f);
    out[(size_t)B_ROWS * D_DIM + H_DIM] = sse[0] / tv;
  }
}

extern "C" void kernel_launch(void* const* d_in, const int* in_sizes, int n_in,
                              void* d_out, int out_size, void* d_ws, size_t ws_size,
                              hipStream_t stream) {
  (void)in_sizes; (void)n_in; (void)out_size; (void)ws_size;
  const float* x     = (const float*)d_in[0];
  const float* W_enc = (const float*)d_in[1];
  const float* b_enc = (const float*)d_in[2];
  const float* W_dec = (const float*)d_in[3];
  const float* b_dec = (const float*)d_in[4];
  float* out = (float*)d_out;
  char* ws = (char*)d_ws;

  u16*  sae    = (u16*)(ws + SAE_OFF);
  u16*  wencb  = (u16*)(ws + WENCB_OFF);
  u16*  wdecb  = (u16*)(ws + WDECB_OFF);
  float* trowp = (float*)(ws + TROW_OFF);
  u32*  candp  = (u32*)(ws + CAND_OFF);
  u32*  cgqp   = (u32*)(ws + CGQ_OFF);
  float* colsum = (float*)(ws + COLSUM_OFF);
  float* sumsq  = (float*)(ws + SUMSQ_OFF);
  float* ssep   = (float*)(ws + SSE_OFF);
  float* counts = out + (size_t)B_ROWS * D_DIM;

  hipLaunchKernelGGL(k_zero,   dim3(33),   dim3(256), 0, stream, counts, colsum);
  hipLaunchKernelGGL(k_prep,   dim3(4608), dim3(256), 0, stream,
                     x, b_dec, (const float4*)W_enc, (const float4*)W_dec,
                     sae, trowp, colsum, sumsq, (ushort4*)wencb, (ushort4*)wdecb);
  hipLaunchKernelGGL(k_gemm,   dim3(512),  dim3(512), 0, stream, sae, wencb, b_enc, trowp, candp, cgqp);
  hipLaunchKernelGGL(k_seldec, dim3(4096), dim3(256), 0, stream, candp, cgqp, sae, wencb, b_enc, W_enc, wdecb, b_dec, x, out, counts, ssep);
  hipLaunchKernelGGL(k_fvu,    dim3(1),    dim3(256), 0, stream, colsum, sumsq, ssep, out);
}

// Round 19
// 183.505 us; speedup vs baseline: 1.1398x; 1.1398x over previous
//
#include <hip/hip_runtime.h>

typedef unsigned short u16;
typedef unsigned int   u32;
typedef unsigned long long u64;

typedef __bf16 bf16x8 __attribute__((ext_vector_type(8)));
typedef float  f32x4  __attribute__((ext_vector_type(4)));

#define B_ROWS   16384
#define D_DIM    256
#define H_DIM    8192
#define THR_C    2.35f
#define QCAP     48          // per-(row, quarter-col-segment) candidate cap

// workspace byte offsets (~29.7 MiB)
#define SAE_OFF    0u          // u16 [16384*256]      sae_in bf16
#define WENCB_OFF  8388608u    // u16 [8192*256]       W_enc bf16
#define WDECB_OFF  12582912u   // u16 [8192*256]       W_dec bf16
#define TROW_OFF   16777216u   // f32 [16384]          per-row threshold
#define CAND_OFF   16842752u   // u32 [16384*4*QCAP]   candidates (bf16val<<16|col)
#define CGQ_OFF    29425664u   // u32 [16384*4]        per-(row,q) counts
#define COLSUM_OFF 29687808u   // f32 [256]
#define SUMSQ_OFF  29688832u   // f32 [1]
#define SSE_OFF    29688836u   // f32 [1]

__device__ __forceinline__ u16 f2bf(float f) {
  u32 u = __float_as_uint(f);
  u32 r = (u + 0x7fffu + ((u >> 16) & 1u)) >> 16;   // RNE
  return (u16)r;
}
__device__ __forceinline__ float bf2f(u16 h) {
  return __uint_as_float(((u32)h) << 16);
}

__device__ __forceinline__ void async_copy16(const void* g, void* l) {
  __builtin_amdgcn_global_load_lds((const __attribute__((address_space(1))) u32*)g,
                                   (__attribute__((address_space(3))) u32*)l,
                                   16, 0, 0);
}

// ---------------- zero counts + accumulators ----------------
__global__ void k_zero(float* counts_out, float* accums) {
  int i = blockIdx.x * 256 + threadIdx.x;
  if (i < H_DIM + 1) counts_out[i] = 0.f;
  if (i < 258) accums[i] = 0.f;
}

// ---------------- merged prep: blocks [0,4096) convert W_enc/W_dec -> bf16;
// ---------------- blocks [4096,4608) do x -> sae bf16 + trow + colsum + sumsq ----------------
__global__ __launch_bounds__(256) void k_prep(const float* __restrict__ x,
                                              const float* __restrict__ bdec,
                                              const float4* __restrict__ wenc,
                                              const float4* __restrict__ wdec,
                                              u16* __restrict__ sae,
                                              float* __restrict__ trow,
                                              float* __restrict__ colsum,
                                              float* __restrict__ sumsq,
                                              ushort4* __restrict__ wencb,
                                              ushort4* __restrict__ wdecb) {
  __shared__ float cssh[256];
  __shared__ float sqsh[4];
  const int bx = blockIdx.x;
  if (bx < 4096) {                       // W conversion branch (no barriers)
    const int i = bx * 256 + threadIdx.x;
    const int half = H_DIM * D_DIM / 4;
    float4 v;
    if (i < half) v = wenc[i]; else v = wdec[i - half];
    ushort4 o;
    o.x = f2bf(v.x); o.y = f2bf(v.y); o.z = f2bf(v.z); o.w = f2bf(v.w);
    if (i < half) wencb[i] = o; else wdecb[i - half] = o;
    return;
  }
  const int blk = bx - 4096;             // x-prep branch
  const int tid = threadIdx.x;
  const int l = tid & 63, w = tid >> 6;
  const float4 bd4 = *(const float4*)(bdec + l * 4);
  float4 cs4 = {0.f, 0.f, 0.f, 0.f};
  float sq = 0.f;
  for (int i = 0; i < 8; ++i) {
    const int row = blk * 32 + w * 8 + i;
    const float4 x4 = *(const float4*)(x + (size_t)row * D_DIM + l * 4);
    float4 s4 = {x4.x - bd4.x, x4.y - bd4.y, x4.z - bd4.z, x4.w - bd4.w};
    ushort4 o;
    o.x = f2bf(s4.x); o.y = f2bf(s4.y); o.z = f2bf(s4.z); o.w = f2bf(s4.w);
    *(ushort4*)(sae + (size_t)row * D_DIM + l * 4) = o;
    cs4.x += x4.x; cs4.y += x4.y; cs4.z += x4.z; cs4.w += x4.w;
    sq += x4.x * x4.x + x4.y * x4.y + x4.z * x4.z + x4.w * x4.w;
    float ss = s4.x * s4.x + s4.y * s4.y + s4.z * s4.z + s4.w * s4.w;
#pragma unroll
    for (int off = 32; off > 0; off >>= 1) ss += __shfl_xor(ss, off);
    if (l == 0) trow[row] = THR_C * sqrtf(ss * (1.0f / 256.0f));
  }
  if (w == 0) { cssh[l * 4 + 0] = cs4.x; cssh[l * 4 + 1] = cs4.y; cssh[l * 4 + 2] = cs4.z; cssh[l * 4 + 3] = cs4.w; }
  __syncthreads();
#pragma unroll
  for (int ww = 1; ww < 4; ++ww) {
    if (w == ww) { cssh[l * 4 + 0] += cs4.x; cssh[l * 4 + 1] += cs4.y; cssh[l * 4 + 2] += cs4.z; cssh[l * 4 + 3] += cs4.w; }
    __syncthreads();
  }
#pragma unroll
  for (int off = 32; off > 0; off >>= 1) sq += __shfl_xor(sq, off);
  if (l == 0) sqsh[w] = sq;
  __syncthreads();
  atomicAdd(&colsum[tid], cssh[tid]);
  if (tid == 0) atomicAdd(sumsq, sqsh[0] + sqsh[1] + sqsh[2] + sqsh[3]);
}

// ---------------- encoder GEMM + threshold filter (r17 champion, byte-identical) ----------------
// counted-vmcnt 3-buffer ring: tiles staged 2 ahead, per-iter
// {s_waitcnt vmcnt(2) + sched_barrier + raw s_barrier -> compute -> epilogue
// -> stage(ci+2)}. vmcnt retires in order; vmcnt(2) waits exactly tile-ci's
// 2 global_load_lds. Top-of-iter barrier proves all waves finished
// compute(ci-1) before stage(ci+2) overwrites buf[(ci-1)%3].
__global__ __launch_bounds__(512, 4) void k_gemm(const u16* __restrict__ sae,
                                                 const u16* __restrict__ wenc,
                                                 const float* __restrict__ benc,
                                                 const float* __restrict__ trow,
                                                 u32* __restrict__ cand,
                                                 u32* __restrict__ cgq) {
  __shared__ __align__(16) u16 ldsw[3][8192];   // 3 x 16 KiB ring (32 cols x 256 k)
  __shared__ u32 lcand[128 * QCAP];             // 24 KiB candidate buffer
  __shared__ u32 lcnt[128];
  const int tid = threadIdx.x;
  const int l   = tid & 63;
  const int w   = tid >> 6;
  const int bid = blockIdx.x;
  const int q   = bid & 3;
  const int m   = bid >> 2;
  const int wr  = w & 3;
  const int wc  = w >> 2;
  const int rbase = m * 128 + wr * 32;
  const int kc  = l >> 4;    // 0..3
  const int r16 = l & 15;

  if (tid < 128) lcnt[tid] = 0u;

  // A fragments: rows rbase + fr*16 + r16, k = ks*32 + kc*8 + j
  bf16x8 a[2][8];
#pragma unroll
  for (int fr = 0; fr < 2; ++fr) {
    const u16* ap = sae + (size_t)(rbase + fr * 16 + r16) * 256 + kc * 8;
#pragma unroll
    for (int ks = 0; ks < 8; ++ks)
      a[fr][ks] = *(const bf16x8*)(ap + ks * 32);
  }
  float trw[2][4];
#pragma unroll
  for (int fr = 0; fr < 2; ++fr)
#pragma unroll
    for (int rr = 0; rr < 4; ++rr)
      trw[fr][rr] = trow[rbase + fr * 16 + kc * 4 + rr];

  const char* wbytes = (const char*)wenc;
  auto stage = [&](int ci, int buf) {
    const int gcol0 = q * 2048 + ci * 32;
#pragma unroll
    for (int i = 0; i < 2; ++i) {
      int L    = i * 8192 + tid * 16;          // linear LDS byte (0..16383)
      int col  = L >> 9;                       // 0..31
      int pblk = (L >> 4) & 31;                // physical 16B chunk in col
      int cblk = pblk ^ (col & 15);            // inverse swizzle on source
      const void* src = wbytes + (size_t)(gcol0 + col) * 512 + (size_t)cblk * 16;
      void* dst = (char*)(&ldsw[buf][0]) + i * 8192 + w * 1024;   // wave-uniform base
      async_copy16(src, dst);
    }
  };

  stage(0, 0);
  stage(1, 1);
  __syncthreads();     // one-time full drain: lcnt init visible + tiles 0,1 ready

  const f32x4 fzero = {0.f, 0.f, 0.f, 0.f};
  int cur = 0;
  for (int ci = 0; ci < 64; ++ci) {
    // tile ci ready: my in-flight loads beyond tile ci are at most tile ci+1's 2
    if (ci < 63) {
      asm volatile("s_waitcnt vmcnt(2)" ::: "memory");
    } else {
      asm volatile("s_waitcnt vmcnt(0)" ::: "memory");
    }
    __builtin_amdgcn_sched_barrier(0);
    __builtin_amdgcn_s_barrier();              // all waves' tile-ci loads landed

    const int gcol0 = q * 2048 + ci * 32;
    const char* bufc = (const char*)(&ldsw[cur][0]);

    const float be = benc[gcol0 + wc * 16 + r16];

    f32x4 acc[2];
    acc[0] = fzero; acc[1] = fzero;

#pragma unroll
    for (int ks = 0; ks < 8; ++ks) {
      const int colL = wc * 16 + r16;          // 0..31
      const int pb = (ks * 4 + kc) ^ r16;      // swizzled 16B chunk
      const bf16x8 bfrag = *(const bf16x8*)(bufc + (size_t)colL * 512 + (size_t)pb * 16);
#pragma unroll
      for (int fr = 0; fr < 2; ++fr)
        acc[fr] = __builtin_amdgcn_mfma_f32_16x16x32_bf16(a[fr][ks], bfrag, acc[fr], 0, 0, 0);
    }

    // epilogue: relu(score+b_enc) > t_row -> append packed candidate to LDS
#pragma unroll
    for (int fr = 0; fr < 2; ++fr) {
#pragma unroll
      for (int rr = 0; rr < 4; ++rr) {
        float v = acc[fr][rr] + be;
        if (v > trw[fr][rr]) {
          const int rowl = wr * 32 + fr * 16 + kc * 4 + rr;
          const int colg = gcol0 + wc * 16 + r16;
          u32 pos = atomicAdd(&lcnt[rowl], 1u);
          if (pos < (u32)QCAP)
            lcand[rowl * QCAP + pos] = ((u32)f2bf(v) << 16) | (u32)colg;
        }
      }
    }

    // stage tile ci+2 into buf[(ci+2)%3] = buf[(ci-1)%3]: all waves passed this
    // iter's barrier => all finished compute(ci-1) reads of that buffer.
    if (ci + 2 < 64) {
      const int sb = cur == 0 ? 2 : cur - 1;   // (ci+2)%3
      stage(ci + 2, sb);
    }
    cur = (cur == 2) ? 0 : cur + 1;
  }

  __syncthreads();     // all epilogue LDS atomics visible before flush

  // coalesced flush: counts + valid candidates
  if (tid < 128) cgq[(size_t)(m * 128 + tid) * 4 + q] = lcnt[tid];
  const int rowl = tid >> 2;                   // 4 threads per row
  const u32 cnt = lcnt[rowl];
  const u32 lim = cnt < (u32)QCAP ? cnt : (u32)QCAP;
  u32* dst = cand + ((size_t)(m * 128 + rowl) * 4 + q) * QCAP;
#pragma unroll
  for (int j = 0; j < QCAP / 4; ++j) {
    const u32 s = (u32)(tid & 3) + 4u * j;
    if (s < lim) dst[s] = lcand[rowl * QCAP + s];
  }
}

// ---------------- wave-wide bitonic sorts (ascending across 64 lanes) ----------------
__device__ __forceinline__ u64 sort64(u64 v, int l) {
#pragma unroll
  for (int k = 2; k <= 64; k <<= 1) {
#pragma unroll
    for (int j = k >> 1; j > 0; j >>= 1) {
      u64 o = __shfl_xor(v, j);
      const bool up    = ((l & k) == 0);
      const bool lower = ((l & j) == 0);
      u64 mn = v < o ? v : o;
      u64 mx = v < o ? o : v;
      v = (up == lower) ? mn : mx;
    }
  }
  return v;
}
__device__ __forceinline__ u32 sort64u(u32 v, int l) {
#pragma unroll
  for (int k = 2; k <= 64; k <<= 1) {
#pragma unroll
    for (int j = k >> 1; j > 0; j >>= 1) {
      u32 o = __shfl_xor(v, j);
      const bool up    = ((l & k) == 0);
      const bool lower = ((l & j) == 0);
      u32 mn = v < o ? v : o;
      u32 mx = v < o ? o : v;
      v = (up == lower) ? mn : mx;
    }
  }
  return v;
}

// ---------------- fused: exact top-32 (wave-cooperative f32 rescore of ranks 25..40)
// ---------------- + counts + decode + sse. 512-thr blocks (8 rows), grid 2048. ----------------
__global__ __launch_bounds__(512) void k_seldec(const u32* __restrict__ cand,
                                                const u32* __restrict__ cgq,
                                                const u16* __restrict__ sae,
                                                const u16* __restrict__ wenc,
                                                const float* __restrict__ benc,
                                                const float* __restrict__ wencf,
                                                const u16* __restrict__ wdecb,
                                                const float* __restrict__ bdec,
                                                const float* __restrict__ x,
                                                float* __restrict__ out,
                                                float* __restrict__ counts,
                                                float* __restrict__ sse) {
  __shared__ float sh_s[8][256];
  __shared__ float essh[8];
  const int l = threadIdx.x & 63;
  const int w = threadIdx.x >> 6;
  const int row = blockIdx.x * 8 + w;
  // stage s = x - b_dec (f32) for this row into LDS (wave-private region)
  const float4 x4  = *(const float4*)(x + (size_t)row * D_DIM + l * 4);
  const float4 bd4 = *(const float4*)(bdec + l * 4);
  {
    float4 s4 = {x4.x - bd4.x, x4.y - bd4.y, x4.z - bd4.z, x4.w - bd4.w};
    *(float4*)(&sh_s[w][l * 4]) = s4;
  }

  const uint4 c4 = *(const uint4*)(cgq + (size_t)row * 4);
  const bool ovf = (c4.x > (u32)QCAP) | (c4.y > (u32)QCAP) | (c4.z > (u32)QCAP) | (c4.w > (u32)QCAP);
  const u32 cum0 = c4.x, cum1 = cum0 + c4.y, cum2 = cum1 + c4.z;
  const u32 T = cum2 + c4.w;
  u64 v;
  if (!ovf && T >= 32u) {          // wave-uniform branch (row is per-wave)
    const u32* cb = cand + (size_t)row * 4 * QCAP;
    auto fetch = [&](u32 p) -> u32 {
      u32 qi, off;
      if (p < cum0)      { qi = 0; off = p; }
      else if (p < cum1) { qi = 1; off = p - cum0; }
      else if (p < cum2) { qi = 2; off = p - cum1; }
      else               { qi = 3; off = p - cum2; }
      return cb[qi * QCAP + off];
    };
    u32 key = ((u32)l < T) ? fetch((u32)l) : 0u;
    key = sort64u(key, l);
    for (u32 p = 64; p < T; p += 64) {
      const u32 pp = p + (u32)l;
      u32 u = (pp < T) ? fetch(pp) : 0u;
      u = sort64u(u, l);
      u32 ur = __shfl(u, 63 - l);
      key = key > ur ? key : ur;      // top-64 of union (bitonic)
      key = sort64u(key, l);
    }
    // keys ascending: lane 63 = bf16-rank 1. Expand to u64: f32 bit pattern
    // (bf16 bits, already <<16 inside key) goes in the HIGH 32 bits (<<32).
    v = key ? ((((u64)(key & 0xffff0000u)) << 32) | (u64)(key & 0x1fffu)) : 0ull;
    // Wave-cooperative f32 rescore of the 16 boundary candidates (bf16 ranks
    // 25..40, held by lanes 24..39). 4 groups x 16 lanes; each group computes
    // 4 candidates; coalesced 16-float reads + 4-step shfl_xor group reduce.
    // Ranks 1..24 / 41+ keep bf16 values (in/out-of-set by ~30-sigma margins).
    const int g  = l >> 4;
    const int gl = l & 15;
    const float* srow = &sh_s[w][gl * 16];
    const float4 sv0 = *(const float4*)(srow + 0);
    const float4 sv1 = *(const float4*)(srow + 4);
    const float4 sv2 = *(const float4*)(srow + 8);
    const float4 sv3 = *(const float4*)(srow + 12);
    auto cscore = [&](int j) -> float {
      const u32 kj = (u32)__shfl((int)key, 24 + g * 4 + j);   // candidate key
      const u32 ti = kj & 0x1fffu;
      const float* wrow = wencf + (size_t)ti * D_DIM + gl * 16;
      const float4 w0 = *(const float4*)(wrow + 0);
      const float4 w1 = *(const float4*)(wrow + 4);
      const float4 w2 = *(const float4*)(wrow + 8);
      const float4 w3 = *(const float4*)(wrow + 12);
      float p = sv0.x * w0.x + sv0.y * w0.y + sv0.z * w0.z + sv0.w * w0.w
              + sv1.x * w1.x + sv1.y * w1.y + sv1.z * w1.z + sv1.w * w1.w
              + sv2.x * w2.x + sv2.y * w2.y + sv2.z * w2.z + sv2.w * w2.w
              + sv3.x * w3.x + sv3.y * w3.y + sv3.z * w3.z + sv3.w * w3.w;
      p += __shfl_xor(p, 1);
      p += __shfl_xor(p, 2);
      p += __shfl_xor(p, 4);
      p += __shfl_xor(p, 8);
      return p;                     // all 16 lanes of the group hold the dot
    };
    const float r0 = cscore(0);
    const float r1 = cscore(1);
    const float r2 = cscore(2);
    const float r3 = cscore(3);
    {
      // deliver candidate c's score to owner lane 24+c (c = g*4+j computed in
      // group c>>2): 4 shfl broadcasts + select. All lanes execute the shfls.
      const int c  = (l - 24) & 63;
      const int sg = ((c >> 2) & 3) * 16;
      const float t0 = __shfl(r0, sg);
      const float t1 = __shfl(r1, sg);
      const float t2 = __shfl(r2, sg);
      const float t3 = __shfl(r3, sg);
      const int cm = c & 3;
      const float ps = cm == 0 ? t0 : (cm == 1 ? t1 : (cm == 2 ? t2 : t3));
      if (l >= 24 && l < 40 && key != 0u) {
        const u32 ti = key & 0x1fffu;
        const float ns = fmaxf(ps + benc[ti], 0.f);   // relu; keys stay non-negative
        v = ((u64)__float_as_uint(ns) << 32) | ti;
      }
    }
    v = sort64(v, l);
  } else {
    // statistically unreachable fallback: exact full-row recompute (bf16)
    v = 0ull;
    const u16* ap = sae + (size_t)row * 256;
    for (int c0 = 0; c0 < H_DIM; c0 += 64) {
      const int col = c0 + l;
      const u16* wp = wenc + (size_t)col * 256;
      float s = benc[col];
      for (int kk = 0; kk < 256; ++kk) s += bf2f(ap[kk]) * bf2f(wp[kk]);
      s = fmaxf(s, 0.f);
      u64 u = ((u64)__float_as_uint(s) << 32) | (u32)col;
      u = sort64(u, l);
      if (c0 == 0) {
        v = u;
      } else {
        u64 ur = __shfl(u, 63 - l);
        v = v > ur ? v : ur;
        v = sort64(v, l);
      }
    }
  }
  // lanes 32..63 hold the top-32 (ascending): per-latent counts
  if (l >= 32) {
    const u32 idx = (u32)(v & 0xffffffffu);
    atomicAdd(&counts[idx], 1.0f);
  }
  // decode from bf16 W_dec (r4-validated shfl-broadcast pattern)
  float ax = 0.f, ay = 0.f, az = 0.f, aw2 = 0.f;
#pragma unroll 8
  for (int j = 0; j < 32; ++j) {
    const u64 t = __shfl(v, 32 + j);
    const float tv = __uint_as_float((u32)(t >> 32));
    const u32 ti = (u32)(t & 0x1fffu);
    const ushort4 wv = *(const ushort4*)(wdecb + (size_t)ti * 256 + l * 4);
    ax += tv * bf2f(wv.x); ay += tv * bf2f(wv.y);
    az += tv * bf2f(wv.z); aw2 += tv * bf2f(wv.w);
  }
  float4 xr;
  xr.x = ax + bd4.x; xr.y = ay + bd4.y; xr.z = az + bd4.z; xr.w = aw2 + bd4.w;
  *(float4*)(out + (size_t)row * 256 + l * 4) = xr;
  const float e0 = xr.x - x4.x, e1 = xr.y - x4.y, e2 = xr.z - x4.z, e3 = xr.w - x4.w;
  float es = e0 * e0 + e1 * e1 + e2 * e2 + e3 * e3;
#pragma unroll
  for (int off = 32; off > 0; off >>= 1) es += __shfl_xor(es, off);
  if (l == 0) essh[w] = es;
  __syncthreads();
  if (threadIdx.x == 0) {
    float s = essh[0] + essh[1] + essh[2] + essh[3]
            + essh[4] + essh[5] + essh[6] + essh[7];
    atomicAdd(sse, s);
  }
}

// ---------------- fvu ----------------
__global__ __launch_bounds__(256) void k_fvu(const float* __restrict__ colsum,
                                             const float* __restrict__ sumsq,
                                             const float* __restrict__ sse,
                                             float* __restrict__ out) {
  __shared__ float red[4];
  const int tid = threadIdx.x;
  const int l = tid & 63;
  const int w = tid >> 6;
  const float c = colsum[tid];
  float p = c * c;
#pragma unroll
  for (int off = 32; off > 0; off >>= 1) p += __shfl_xor(p, off);
  if (l == 0) red[w] = p;
  __syncthreads();
  if (tid == 0) {
    const float tv = sumsq[0] - (red[0] + red[1] + red[2] + red[3]) * (1.0f / 16384.0f);
    out[(size_t)B_ROWS * D_DIM + H_DIM] = sse[0] / tv;
  }
}

extern "C" void kernel_launch(void* const* d_in, const int* in_sizes, int n_in,
                              void* d_out, int out_size, void* d_ws, size_t ws_size,
                              hipStream_t stream) {
  (void)in_sizes; (void)n_in; (void)out_size; (void)ws_size;
  const float* x     = (const float*)d_in[0];
  const float* W_enc = (const float*)d_in[1];
  const float* b_enc = (const float*)d_in[2];
  const float* W_dec = (const float*)d_in[3];
  const float* b_dec = (const float*)d_in[4];
  float* out = (float*)d_out;
  char* ws = (char*)d_ws;

  u16*  sae    = (u16*)(ws + SAE_OFF);
  u16*  wencb  = (u16*)(ws + WENCB_OFF);
  u16*  wdecb  = (u16*)(ws + WDECB_OFF);
  float* trowp = (float*)(ws + TROW_OFF);
  u32*  candp  = (u32*)(ws + CAND_OFF);
  u32*  cgqp   = (u32*)(ws + CGQ_OFF);
  float* colsum = (float*)(ws + COLSUM_OFF);
  float* sumsq  = (float*)(ws + SUMSQ_OFF);
  float* ssep   = (float*)(ws + SSE_OFF);
  float* counts = out + (size_t)B_ROWS * D_DIM;

  hipLaunchKernelGGL(k_zero,   dim3(33),   dim3(256), 0, stream, counts, colsum);
  hipLaunchKernelGGL(k_prep,   dim3(4608), dim3(256), 0, stream,
                     x, b_dec, (const float4*)W_enc, (const float4*)W_dec,
                     sae, trowp, colsum, sumsq, (ushort4*)wencb, (ushort4*)wdecb);
  hipLaunchKernelGGL(k_gemm,   dim3(512),  dim3(512), 0, stream, sae, wencb, b_enc, trowp, candp, cgqp);
  hipLaunchKernelGGL(k_seldec, dim3(2048), dim3(512), 0, stream, candp, cgqp, sae, wencb, b_enc, W_enc, wdecb, b_dec, x, out, counts, ssep);
  hipLaunchKernelGGL(k_fvu,    dim3(1),    dim3(256), 0, stream, colsum, sumsq, ssep, out);
}